// Round 14
// baseline (448.291 us; speedup 1.0000x reference)
//
#include <hip/hip_runtime.h>

// VQ-VAE vector quantizer, MI355X (gfx950)
// B=16, C=256, H=W=32 -> N=16384 pixels; K=8192 codes.
// R17: R16 killed the LDS-pool hypothesis (LDS exactly 65536, occupancy
// still 11.4%). Consolidated occupancy law across 8 rounds: 2 waves/SIMD
// iff VGPR_Count <= 128 (R7/R10/R11/R12 = 104-128 -> ~22%; R9/R15/R16 =
// 136-140 -> ~11.5%), independent of LDS at 64KB. R15/R16's kt=2 + ring
// structure is 1.65x better PER WAVE (29% MfmaUtil at 1 wave vs R11's
// 35% at 2) -- it just needs its second wave: shave 12 arch regs.
// Fix: amdgpu_waves_per_eu(2) invokes the proven 128/128 arch/acc split
// (R10 mechanism: backend moves accumulators + overflow to free AGPRs as
// cheap v_accvgpr movs, NOT scratch, when residual arch fits the cap).
// Residual arch ~ ring 64 + ah/al 16 + bs/bi 16 + Zr 8 + addr ~20 = ~124
// <= 128. Numerics bit-identical to R16 (passed, absmax 0).
// Canaries: WRITE_SIZE ~1MB (balloon => cap forced scratch -> revert to
// R11); VGPR <= 128; Occupancy ~22%; LDS_Block_Size 65536.

typedef _Float16 f16;
typedef __attribute__((ext_vector_type(8))) _Float16 f16x8;
typedef __attribute__((ext_vector_type(4))) float f32x4;

#define NPIX   16384      // B*H*W
#define CDIM   256
#define KCODE  8192

// ---------------- K0: fused prep ----------------
// bid <  512 : codebook -> packed MFMA B-fragments (hi/lo limbs, x8192)
// bid <  576 : z -> zhi/zlo fp16 limbs + z_sq (bit-exact pairwise)
// bid <  608 : e_sq (bit-exact numpy pairwise, thread per row)
// bid == 608 : init best/lossac/cnt (replaces 3 hipMemsetAsync)
__global__ void k_prep(const float* __restrict__ z, const float* __restrict__ cb,
                       f16* __restrict__ zhi, f16* __restrict__ zlo,
                       float* __restrict__ zsq,
                       f16* __restrict__ bfh, f16* __restrict__ bfl,
                       float* __restrict__ esq,
                       unsigned long long* __restrict__ best,
                       float* __restrict__ lossac, int* __restrict__ cnt) {
  int bid = blockIdx.x;
  int t   = threadIdx.x;
  if (bid < 512) {
    // ---- cbsplit: bf[((kb*8+cs)*64+lane)*8+j] =
    //      limb(cb[kb*16+(lane&15)][cs*32+((lane>>4)&3)*8+j]) ----
    int kb = bid;
#pragma unroll
    for (int half = 0; half < 2; ++half) {
      int o    = half * 256 + t;         // o = cs*64 + lane, 0..511
      int lane = o & 63;
      int cs   = o >> 6;
      int code = kb * 16 + (lane & 15);
      int c0   = cs * 32 + ((lane >> 4) & 3) * 8;
      const float* src = cb + (size_t)code * CDIM + c0;
      float4 v0 = *(const float4*)(src);
      float4 v1 = *(const float4*)(src + 4);
      float e[8] = {v0.x, v0.y, v0.z, v0.w, v1.x, v1.y, v1.z, v1.w};
      f16x8 h8, l8;
#pragma unroll
      for (int j = 0; j < 8; ++j) {
        float ej = e[j] * 8192.0f;
        f16 h = (f16)ej;
        h8[j] = h;
        l8[j] = (f16)((ej - (float)h) * 4096.0f);
      }
      size_t off = ((size_t)kb * 512 + o) * 8;
      *(f16x8*)(bfh + off) = h8;
      *(f16x8*)(bfl + off) = l8;
    }
  } else if (bid < 576) {
    // ---- zprep: limbs + zsq (numpy pairwise fp32 order, contract off) ----
#pragma clang fp contract(off)
    int n = (bid - 512) * 256 + t;
    int b = n >> 10, p = n & 1023;
    const float* src = z + (size_t)b * CDIM * 1024 + p;
    f16* dh = zhi + (size_t)n * CDIM;
    f16* dl = zlo + (size_t)n * CDIM;
    float half_[2];
    for (int m = 0; m < 2; ++m) {
      float r[8];
#pragma unroll
      for (int j = 0; j < 8; ++j) r[j] = 0.0f;
      for (int i = 0; i < 16; ++i) {
        f16x8 h8, l8;
#pragma unroll
        for (int j = 0; j < 8; ++j) {
          float v = src[(size_t)(m * 128 + i * 8 + j) * 1024];  // coalesced
          r[j] = r[j] + v * v;                                  // mul then add
          f16 h = (f16)v;
          h8[j] = h;
          l8[j] = (f16)((v - (float)h) * 4096.0f);              // scaled low limb
        }
        *(f16x8*)(dh + m * 128 + i * 8) = h8;
        *(f16x8*)(dl + m * 128 + i * 8) = l8;
      }
      half_[m] = ((r[0] + r[1]) + (r[2] + r[3])) + ((r[4] + r[5]) + (r[6] + r[7]));
    }
    zsq[n] = half_[0] + half_[1];
  } else if (bid < 608) {
    // ---- esq: bit-exact numpy pairwise ----
#pragma clang fp contract(off)
    int row = (bid - 576) * 256 + t;
    const float* src = cb + (size_t)row * CDIM;
    float half_[2];
    for (int m = 0; m < 2; ++m) {
      float r[8];
#pragma unroll
      for (int j = 0; j < 8; ++j) r[j] = 0.0f;
      for (int i = 0; i < 16; ++i) {
        float4 v0 = *(const float4*)(src + m * 128 + i * 8);
        float4 v1 = *(const float4*)(src + m * 128 + i * 8 + 4);
        r[0] = r[0] + v0.x * v0.x;  r[1] = r[1] + v0.y * v0.y;
        r[2] = r[2] + v0.z * v0.z;  r[3] = r[3] + v0.w * v0.w;
        r[4] = r[4] + v1.x * v1.x;  r[5] = r[5] + v1.y * v1.y;
        r[6] = r[6] + v1.z * v1.z;  r[7] = r[7] + v1.w * v1.w;
      }
      half_[m] = ((r[0] + r[1]) + (r[2] + r[3])) + ((r[4] + r[5]) + (r[6] + r[7]));
    }
    esq[row] = half_[0] + half_[1];
  } else {
    // ---- init: best = 0xFF.., lossac = 0, cnt[8] = 0 ----
#pragma unroll 4
    for (int i = 0; i < 64; ++i)
      best[(size_t)i * 256 + t] = ~0ull;
    if (t == 0) *lossac = 0.0f;
    if (t < 8) cnt[t] = 0;
  }
}

// ---------------- K2: fused score GEMM + argmin ----------------
// 2048 blocks x 256 threads (4 waves = 2 wh x 2 wk). Job = (kslice, ptile)
// claimed at runtime: kslice = this block's actual XCD id (1 MB hi+lo
// packed codebook slice stays L2-resident per XCD), ptile = per-slice
// ticket. Pigeonhole: a block seeing all 8 counters >= 256 implies 2048
// claims by others -- impossible with 2048 blocks each claiming <= 1.
// A-tile 64px x 256c hi+lo in EXACTLY 64KB static LDS (16B xor swizzle);
// s_job lives in smem[0..7] (consumed before staging overwrites it).
// B prefetched through a 4-slot register ring, lookahead 3, issued per-cs
// inside the compute stream (counted vmcnt). Wave (wh,wk): 32px x 32
// codes/iter (kt=2), 16 iters. waves_per_eu(2) -> 128/128 arch/acc split
// (R10 mechanism): accs + overflow to AGPR, arch <= 128, 2 waves/SIMD.
#define PREFETCH(SLOT, G2) do {                                               \
    int g2_  = (G2) > 127 ? 127 : (G2);    /* clamp: uniform, redundant */    \
    int kbq_ = kslice * 64 + (g2_ >> 3) * 4 + wk * 2;                         \
    int cs2_ = g2_ & 7;                                                       \
    _Pragma("unroll")                                                         \
    for (int kt_ = 0; kt_ < 2; ++kt_) {                                       \
      size_t off_ = (((size_t)(kbq_ + kt_) * 8 + cs2_) * 64 + lane) * 8;      \
      Bh[SLOT][kt_] = *(const f16x8*)(bfh + off_);                            \
      Bl[SLOT][kt_] = *(const f16x8*)(bfl + off_);                            \
    } } while (0)

__launch_bounds__(256)
__attribute__((amdgpu_waves_per_eu(2)))
__global__ void k_score(const f16* __restrict__ bfh, const f16* __restrict__ bfl,
                        const f16* __restrict__ zhi, const f16* __restrict__ zlo,
                        const float* __restrict__ esq, const float* __restrict__ zsq,
                        int* __restrict__ cnt,
                        unsigned long long* __restrict__ best) {
  __shared__ __align__(16) char smem[65536];   // total block LDS: exactly 64KB
  f16* sAh = (f16*)smem;               // 32 KB
  f16* sAl = (f16*)(smem + 32768);     // 32 KB
  int t = threadIdx.x;
  int wave = t >> 6, lane = t & 63;
  int quad = lane >> 4, l15 = lane & 15;
  int wh = wave & 1;                   // pixel half: rows [wh*32, wh*32+32)
  int wk = wave >> 1;                  // code strip 0..1 (32 codes each)

  // ---- claim (kslice, ptile) aligned to the real XCD ----
  // s_job borrows smem[0..7]; it is fully consumed (read into registers by
  // all threads) before the staging phase overwrites byte 0.
  int* s_job = (int*)smem;
  if (t == 0) {
    unsigned xcc;
    asm volatile("s_getreg_b32 %0, hwreg(HW_REG_XCC_ID)" : "=s"(xcc));
    int x = (int)(xcc & 7u);
    int pt = -1, ks = 0;
    for (int trial = 0; trial < 16 && pt < 0; ++trial) {
      int j = (x + trial) & 7;
      int tk = atomicAdd(&cnt[j], 1);
      if (tk < 256) { pt = tk; ks = j; }
    }
    if (pt < 0) pt = 0;                // unreachable (see proof above)
    s_job[0] = pt; s_job[1] = ks;
  }
  __syncthreads();
  int ptile  = s_job[0];
  int kslice = s_job[1];
  __syncthreads();                     // WAR: all reads done before staging writes
  int p0 = ptile * 64;

  // ---- stage A-tile (hi & lo), xor-swizzled at 16B granularity ----
  {
    int r = t >> 2, seg = t & 3;
    const uint4* gh = (const uint4*)zhi + ((size_t)(p0 + r)) * 32;
    const uint4* gl = (const uint4*)zlo + ((size_t)(p0 + r)) * 32;
    uint4* sh = (uint4*)sAh + r * 32;
    uint4* sl = (uint4*)sAl + r * 32;
#pragma unroll
    for (int j = 0; j < 8; ++j) {
      int blk = seg * 8 + j;
      int sb = blk ^ (r & 7);
      sh[sb] = gh[blk];
      sl[sb] = gl[blk];
    }
  }

  // Z for my 8 pixel rows (C/D layout: row = quad*4 + reg)
  float Zr[8];
#pragma unroll
  for (int rt = 0; rt < 2; ++rt)
#pragma unroll
    for (int rr = 0; rr < 4; ++rr)
      Zr[rt * 4 + rr] = zsq[p0 + wh * 32 + rt * 16 + quad * 4 + rr];

  __syncthreads();

  float bs[8];
  int   bi[8];
#pragma unroll
  for (int j = 0; j < 8; ++j) { bs[j] = 3.0e38f; bi[j] = 0; }

  const f32x4 vzero = {0.0f, 0.0f, 0.0f, 0.0f};

  // ---- main loop: kt=2 compute with 4-slot ring B prefetch, lookahead 3 ----
  // Global cs index g = iter*8 + c; slot = g & 3 (8 % 4 == 0 -> phase is
  // compile-time across iters). Slot written at g, read at g+3.
  f16x8 Bh[4][2], Bl[4][2];
  PREFETCH(0, 0);
  PREFETCH(1, 1);
  PREFETCH(2, 2);
#pragma unroll 1
  for (int iter = 0; iter < 16; ++iter) {
    int kbase = kslice * 1024 + iter * 64 + wk * 32;
    f32x4 hh[2][2], mx[2][2];
#pragma unroll
    for (int rt = 0; rt < 2; ++rt)
#pragma unroll
      for (int kt = 0; kt < 2; ++kt) { hh[rt][kt] = vzero; mx[rt][kt] = vzero; }

#pragma unroll
    for (int c = 0; c < 8; ++c) {
      // issue next ring slot's 4 loads inside the compute stream
      PREFETCH((c + 3) & 3, iter * 8 + c + 3);
      f16x8 ah[2], al[2];
#pragma unroll
      for (int rt = 0; rt < 2; ++rt) {
        int px = wh * 32 + rt * 16 + l15;
        int sb = (c * 4 + quad) ^ (px & 7);
        int eo = px * 256 + sb * 8;          // f16 units
        ah[rt] = *(const f16x8*)(sAh + eo);
        al[rt] = *(const f16x8*)(sAl + eo);
      }
#pragma unroll
      for (int rt = 0; rt < 2; ++rt)
#pragma unroll
        for (int kt = 0; kt < 2; ++kt) {
          hh[rt][kt] = __builtin_amdgcn_mfma_f32_16x16x32_f16(ah[rt], Bh[c & 3][kt], hh[rt][kt], 0, 0, 0);
          mx[rt][kt] = __builtin_amdgcn_mfma_f32_16x16x32_f16(ah[rt], Bl[c & 3][kt], mx[rt][kt], 0, 0, 0);
          mx[rt][kt] = __builtin_amdgcn_mfma_f32_16x16x32_f16(al[rt], Bh[c & 3][kt], mx[rt][kt], 0, 0, 0);
        }
    }

    // epilogue: replicate ref's fp32 rounding: d = fl(fl(Z - 2c) + es)
    // 2c = hh/4096 (exact scale) + mx/2^24 (one fmaf rounding)
#pragma unroll
    for (int kt = 0; kt < 2; ++kt) {
      int k = kbase + kt * 16 + l15;
      float es = esq[k];
#pragma unroll
      for (int rt = 0; rt < 2; ++rt)
#pragma unroll
        for (int rr = 0; rr < 4; ++rr) {
          float v = hh[rt][kt][rr] * 2.44140625e-4f;                       // /4096, exact
          float w = fmaf(mx[rt][kt][rr], 5.9604644775390625e-8f, v);       // ~2*cross
          float d = (Zr[rt * 4 + rr] - w) + es;                            // two fp32 roundings
          int j = rt * 4 + rr;
          if (d < bs[j]) { bs[j] = d; bi[j] = k; }                         // first-index on ties
        }
    }
  }

  // ---- reduce: 16 lanes of each quad -> LDS -> across waves ----
  __syncthreads();                          // A-tile dead; reuse LDS
  unsigned long long* red = (unsigned long long*)smem;   // 4 waves x 32 rows
#pragma unroll
  for (int j = 0; j < 8; ++j) {
    float s = bs[j]; int i_ = bi[j];
#pragma unroll
    for (int m = 1; m <= 8; m <<= 1) {
      float s2 = __shfl_xor(s, m);
      int   i2 = __shfl_xor(i_, m);
      if (s2 < s || (s2 == s && i2 < i_)) { s = s2; i_ = i2; }
    }
    if (l15 == 0) {
      int row32 = ((j >> 2) << 4) + (quad << 2) + (j & 3);   // rt*16 + quad*4 + rr
      unsigned u = __float_as_uint(s);
      u = (u & 0x80000000u) ? ~u : (u | 0x80000000u);        // order-preserving map
      red[wave * 32 + row32] = ((unsigned long long)u << 32) | (unsigned)i_;
    }
  }
  __syncthreads();
  // waves (wh) and (wh+2) cover the same 32 pixel rows with disjoint codes
  if (wave == 0) {
    int wh2 = lane >> 5, r31 = lane & 31;
    unsigned long long a = red[wh2 * 32 + r31];
    unsigned long long b = red[(wh2 + 2) * 32 + r31];
    if (b < a) a = b;
    atomicMin(&best[p0 + lane], a);
  }
}

// ---------------- K3: gather quantized, write codes, accumulate loss ----------------
__global__ void k_gather(const float* __restrict__ z, const float* __restrict__ cb,
                         const unsigned long long* __restrict__ best,
                         float* __restrict__ out_codes, float* __restrict__ out_q,
                         float* __restrict__ lossac) {
  int b  = blockIdx.x >> 4;
  int cg = blockIdx.x & 15;
  int t  = threadIdx.x;
  int idx[4];
#pragma unroll
  for (int pi = 0; pi < 4; ++pi) {
    int p = t + pi * 256;
    unsigned long long pk = best[b * 1024 + p];
    idx[pi] = (int)(unsigned)(pk & 0xffffffffu);
    if (cg == 0) out_codes[b * 1024 + p] = (float)idx[pi];
  }
  float lsum = 0.0f;
#pragma unroll
  for (int ci = 0; ci < 16; ++ci) {
    int c = cg * 16 + ci;
#pragma unroll
    for (int pi = 0; pi < 4; ++pi) {
      int p = t + pi * 256;
      float q  = cb[(size_t)idx[pi] * CDIM + c];
      size_t o = ((size_t)(b * CDIM + c)) * 1024 + p;
      float zv = z[o];
      float d  = q - zv;
      out_q[o] = zv + d;                 // straight-through: same op order as reference
      lsum = fmaf(d, d, lsum);
    }
  }
#pragma unroll
  for (int m = 32; m >= 1; m >>= 1) lsum += __shfl_xor(lsum, m);
  __shared__ float wsum[4];
  if ((t & 63) == 0) wsum[t >> 6] = lsum;
  __syncthreads();
  if (t == 0) atomicAdd(lossac, wsum[0] + wsum[1] + wsum[2] + wsum[3]);
}

// ---------------- K4: finalize loss scalar ----------------
__global__ void k_final(const float* __restrict__ lossac, float* __restrict__ out_loss) {
  if (threadIdx.x == 0) out_loss[0] = lossac[0] * (1.25f / 4194304.0f);
}

extern "C" void kernel_launch(void* const* d_in, const int* in_sizes, int n_in,
                              void* d_out, int out_size, void* d_ws, size_t ws_size,
                              hipStream_t stream) {
  (void)in_sizes; (void)n_in; (void)out_size; (void)ws_size;
  const float* z  = (const float*)d_in[0];
  const float* cb = (const float*)d_in[1];
  float* outf = (float*)d_out;

  char* ws = (char*)d_ws;
  f16*   bfh  = (f16*)ws;                                   // 4 MB packed B-frag hi
  f16*   bfl  = (f16*)(ws + (4 << 20));                     // 4 MB packed B-frag lo
  float* esq  = (float*)(ws + (8 << 20));                   // 32 KB
  unsigned long long* best = (unsigned long long*)(ws + (8 << 20) + 32768);  // 128 KB
  float* lossac = (float*)(ws + (8 << 20) + 32768 + 131072);                 // 4 B (pad 256)
  float* zsq    = (float*)(ws + (8 << 20) + 32768 + 131072 + 256);           // 64 KB
  int*   cnt    = (int*)  (ws + (8 << 20) + 32768 + 131072 + 256 + 65536);   // 32 B

  // scratch inside d_out's quantized region (overwritten by k_gather afterwards)
  f16* zhi = (f16*)(outf + 16384);                          // 8 MB
  f16* zlo = zhi + (size_t)NPIX * CDIM;                     // 8 MB

  k_prep   <<<609,  256, 0, stream>>>(z, cb, zhi, zlo, zsq, bfh, bfl, esq,
                                      best, lossac, cnt);
  k_score  <<<2048, 256, 0, stream>>>(bfh, bfl, zhi, zlo, esq, zsq, cnt, best);
  k_gather <<<256,  256, 0, stream>>>(z, cb, best, outf, outf + 16384, lossac);
  k_final  <<<1,    64,  0, stream>>>(lossac, outf + 16384 + (size_t)NPIX * CDIM);
}

// Round 16
// 342.514 us; speedup vs baseline: 1.3088x; 1.3088x over previous
//
#include <hip/hip_runtime.h>

// VQ-VAE vector quantizer, MI355X (gfx950)
// B=16, C=256, H=W=32 -> N=16384 pixels; K=8192 codes.
// R19: R18 died in-container twice with no counters; its only unproven
// element was the new 2-thread zprep split. This round removes it:
// EVERY component here has a passing bench. R12 k_prep exactly (609
// blocks; benched R9/R12/R13/R14 runs) + R11 k_score exactly (benched
// Round 8: 256.6us, VGPR 128, 2 waves/SIMD, MfmaUtil 35%).
// Design-space laws measured across R4-R17 (all alternatives worse):
//   1) 2 waves/SIMD iff arch VGPR <= 128 (hard cliff; waves_per_eu
//      attributes split 128/128 arch/acc and spill if arch > 128).
//   2) B-prefetch depth and the 128-reg cap are mutually exclusive;
//      R11's full-iter B dbuf at exactly 128 regs is the constrained
//      optimum (R15/R16 deeper-per-wave -> 1 wave/SIMD; R17 capped ring
//      -> AGPR churn).
//   3) A-in-regs is defeated by rematerialization (R12); bigger tiles
//      serialize staging (R14); L2-traffic cuts are null -- vmem cost =
//      bytes-to-registers (R14).
// Canaries: k_score VGPR=128, Occupancy ~22%, WRITE ~1MB, FETCH ~85MB.

typedef _Float16 f16;
typedef __attribute__((ext_vector_type(8))) _Float16 f16x8;
typedef __attribute__((ext_vector_type(4))) float f32x4;

#define NPIX   16384      // B*H*W
#define CDIM   256
#define KCODE  8192

// ---------------- K0: fused prep (R12 verbatim) ----------------
// bid <  512 : codebook -> packed MFMA B-fragments (hi/lo limbs, x8192)
// bid <  576 : z -> zhi/zlo fp16 limbs + z_sq (bit-exact pairwise)
// bid <  608 : e_sq (bit-exact numpy pairwise, thread per row)
// bid == 608 : init best/lossac/cnt (replaces 3 hipMemsetAsync)
__global__ void k_prep(const float* __restrict__ z, const float* __restrict__ cb,
                       f16* __restrict__ zhi, f16* __restrict__ zlo,
                       float* __restrict__ zsq,
                       f16* __restrict__ bfh, f16* __restrict__ bfl,
                       float* __restrict__ esq,
                       unsigned long long* __restrict__ best,
                       float* __restrict__ lossac, int* __restrict__ cnt) {
  int bid = blockIdx.x;
  int t   = threadIdx.x;
  if (bid < 512) {
    // ---- cbsplit: bf[((kb*8+cs)*64+lane)*8+j] =
    //      limb(cb[kb*16+(lane&15)][cs*32+((lane>>4)&3)*8+j]) ----
    int kb = bid;
#pragma unroll
    for (int half = 0; half < 2; ++half) {
      int o    = half * 256 + t;         // o = cs*64 + lane, 0..511
      int lane = o & 63;
      int cs   = o >> 6;
      int code = kb * 16 + (lane & 15);
      int c0   = cs * 32 + ((lane >> 4) & 3) * 8;
      const float* src = cb + (size_t)code * CDIM + c0;
      float4 v0 = *(const float4*)(src);
      float4 v1 = *(const float4*)(src + 4);
      float e[8] = {v0.x, v0.y, v0.z, v0.w, v1.x, v1.y, v1.z, v1.w};
      f16x8 h8, l8;
#pragma unroll
      for (int j = 0; j < 8; ++j) {
        float ej = e[j] * 8192.0f;
        f16 h = (f16)ej;
        h8[j] = h;
        l8[j] = (f16)((ej - (float)h) * 4096.0f);
      }
      size_t off = ((size_t)kb * 512 + o) * 8;
      *(f16x8*)(bfh + off) = h8;
      *(f16x8*)(bfl + off) = l8;
    }
  } else if (bid < 576) {
    // ---- zprep: limbs + zsq (numpy pairwise fp32 order, contract off) ----
#pragma clang fp contract(off)
    int n = (bid - 512) * 256 + t;
    int b = n >> 10, p = n & 1023;
    const float* src = z + (size_t)b * CDIM * 1024 + p;
    f16* dh = zhi + (size_t)n * CDIM;
    f16* dl = zlo + (size_t)n * CDIM;
    float half_[2];
    for (int m = 0; m < 2; ++m) {
      float r[8];
#pragma unroll
      for (int j = 0; j < 8; ++j) r[j] = 0.0f;
      for (int i = 0; i < 16; ++i) {
        f16x8 h8, l8;
#pragma unroll
        for (int j = 0; j < 8; ++j) {
          float v = src[(size_t)(m * 128 + i * 8 + j) * 1024];  // coalesced
          r[j] = r[j] + v * v;                                  // mul then add
          f16 h = (f16)v;
          h8[j] = h;
          l8[j] = (f16)((v - (float)h) * 4096.0f);              // scaled low limb
        }
        *(f16x8*)(dh + m * 128 + i * 8) = h8;
        *(f16x8*)(dl + m * 128 + i * 8) = l8;
      }
      half_[m] = ((r[0] + r[1]) + (r[2] + r[3])) + ((r[4] + r[5]) + (r[6] + r[7]));
    }
    zsq[n] = half_[0] + half_[1];
  } else if (bid < 608) {
    // ---- esq: bit-exact numpy pairwise ----
#pragma clang fp contract(off)
    int row = (bid - 576) * 256 + t;
    const float* src = cb + (size_t)row * CDIM;
    float half_[2];
    for (int m = 0; m < 2; ++m) {
      float r[8];
#pragma unroll
      for (int j = 0; j < 8; ++j) r[j] = 0.0f;
      for (int i = 0; i < 16; ++i) {
        float4 v0 = *(const float4*)(src + m * 128 + i * 8);
        float4 v1 = *(const float4*)(src + m * 128 + i * 8 + 4);
        r[0] = r[0] + v0.x * v0.x;  r[1] = r[1] + v0.y * v0.y;
        r[2] = r[2] + v0.z * v0.z;  r[3] = r[3] + v0.w * v0.w;
        r[4] = r[4] + v1.x * v1.x;  r[5] = r[5] + v1.y * v1.y;
        r[6] = r[6] + v1.z * v1.z;  r[7] = r[7] + v1.w * v1.w;
      }
      half_[m] = ((r[0] + r[1]) + (r[2] + r[3])) + ((r[4] + r[5]) + (r[6] + r[7]));
    }
    esq[row] = half_[0] + half_[1];
  } else {
    // ---- init: best = 0xFF.., lossac = 0, cnt[8] = 0 ----
#pragma unroll 4
    for (int i = 0; i < 64; ++i)
      best[(size_t)i * 256 + t] = ~0ull;
    if (t == 0) *lossac = 0.0f;
    if (t < 8) cnt[t] = 0;
  }
}

// ---------------- K2: fused score GEMM + argmin (R11 verbatim) ----------------
// 2048 blocks x 256 threads (4 waves = 2 wh x 2 wk). Job = (kslice, ptile)
// claimed at runtime: kslice = this block's actual XCD id (packed codebook
// slice L2-resident per XCD), ptile = per-slice ticket. Pigeonhole: a
// block seeing all 8 counters >= 256 implies 2048 claims by others --
// impossible with 2048 blocks each claiming <= 1.
// A-tile 64px x 256c hi+lo in 64KB dynamic LDS (16B xor swizzle), read
// per-cs. B double-buffered one full iteration ahead in registers
// (B0/B1, 16 f16x8 each) -> counted vmcnt, L2 latency hidden.
// Wave (wh,wk): 32px x 16 codes/iter, 32 iters. Measured: VGPR 128,
// 2 waves/SIMD, MfmaUtil 35%, 256.6us.
#define LOADB(Bset, it) do {                                                  \
    int kbq_ = kslice * 64 + (it) * 2 + wk;                                   \
    size_t base_ = (size_t)kbq_ * 4096 + (size_t)lane * 8;                    \
    _Pragma("unroll")                                                         \
    for (int cs_ = 0; cs_ < 8; ++cs_) {                                       \
      Bset[2*cs_]   = *(const f16x8*)(bfh + base_ + (size_t)cs_ * 512);       \
      Bset[2*cs_+1] = *(const f16x8*)(bfl + base_ + (size_t)cs_ * 512);       \
    } } while (0)

#define COMPUTE(Bset, it) do {                                                \
    int kbase_ = kslice * 1024 + (it) * 32 + wk * 16;                         \
    f32x4 hh[2], mx[2];                                                       \
    _Pragma("unroll")                                                         \
    for (int rt = 0; rt < 2; ++rt) { hh[rt] = vzero; mx[rt] = vzero; }        \
    _Pragma("unroll")                                                         \
    for (int cs = 0; cs < 8; ++cs) {                                          \
      f16x8 ah[2], al[2];                                                     \
      _Pragma("unroll")                                                       \
      for (int rt = 0; rt < 2; ++rt) {                                        \
        int px = wh * 32 + rt * 16 + l15;                                     \
        int sb = (cs * 4 + quad) ^ (px & 7);                                  \
        int eo = px * 256 + sb * 8;          /* f16 units */                  \
        ah[rt] = *(const f16x8*)(sAh + eo);                                   \
        al[rt] = *(const f16x8*)(sAl + eo);                                   \
      }                                                                       \
      _Pragma("unroll")                                                       \
      for (int rt = 0; rt < 2; ++rt) {                                        \
        hh[rt] = __builtin_amdgcn_mfma_f32_16x16x32_f16(ah[rt], Bset[2*cs],   hh[rt], 0, 0, 0); \
        mx[rt] = __builtin_amdgcn_mfma_f32_16x16x32_f16(ah[rt], Bset[2*cs+1], mx[rt], 0, 0, 0); \
        mx[rt] = __builtin_amdgcn_mfma_f32_16x16x32_f16(al[rt], Bset[2*cs],   mx[rt], 0, 0, 0); \
      }                                                                       \
    }                                                                         \
    {                                                                         \
      int k = kbase_ + l15;                                                   \
      float es = esq[k];                                                      \
      _Pragma("unroll")                                                       \
      for (int rt = 0; rt < 2; ++rt)                                          \
        _Pragma("unroll")                                                     \
        for (int rr = 0; rr < 4; ++rr) {                                      \
          float v = hh[rt][rr] * 2.44140625e-4f;                   /* exact */\
          float w = fmaf(mx[rt][rr], 5.9604644775390625e-8f, v);              \
          float d = (Zr[rt * 4 + rr] - w) + es;                               \
          int j = rt * 4 + rr;                                                \
          if (d < bs[j]) { bs[j] = d; bi[j] = k; }                            \
        }                                                                     \
    } } while (0)

__launch_bounds__(256)
__global__ void k_score(const f16* __restrict__ bfh, const f16* __restrict__ bfl,
                        const f16* __restrict__ zhi, const f16* __restrict__ zlo,
                        const float* __restrict__ esq, const float* __restrict__ zsq,
                        int* __restrict__ cnt,
                        unsigned long long* __restrict__ best) {
  extern __shared__ char smem[];
  f16* sAh = (f16*)smem;               // 32 KB
  f16* sAl = (f16*)(smem + 32768);     // 32 KB
  int t = threadIdx.x;
  int wave = t >> 6, lane = t & 63;
  int quad = lane >> 4, l15 = lane & 15;
  int wh = wave & 1;                   // pixel half: rows [wh*32, wh*32+32)
  int wk = wave >> 1;                  // code strip 0..1

  // ---- claim (kslice, ptile) aligned to the real XCD ----
  __shared__ int s_job[2];
  if (t == 0) {
    unsigned xcc;
    asm volatile("s_getreg_b32 %0, hwreg(HW_REG_XCC_ID)" : "=s"(xcc));
    int x = (int)(xcc & 7u);
    int pt = -1, ks = 0;
    for (int trial = 0; trial < 16 && pt < 0; ++trial) {
      int j = (x + trial) & 7;
      int tk = atomicAdd(&cnt[j], 1);
      if (tk < 256) { pt = tk; ks = j; }
    }
    if (pt < 0) pt = 0;                // unreachable (see proof above)
    s_job[0] = pt; s_job[1] = ks;
  }
  __syncthreads();
  int ptile  = s_job[0];
  int kslice = s_job[1];
  int p0 = ptile * 64;

  // ---- stage A-tile (hi & lo), xor-swizzled at 16B granularity ----
  {
    int r = t >> 2, seg = t & 3;
    const uint4* gh = (const uint4*)zhi + ((size_t)(p0 + r)) * 32;
    const uint4* gl = (const uint4*)zlo + ((size_t)(p0 + r)) * 32;
    uint4* sh = (uint4*)sAh + r * 32;
    uint4* sl = (uint4*)sAl + r * 32;
#pragma unroll
    for (int j = 0; j < 8; ++j) {
      int blk = seg * 8 + j;
      int sb = blk ^ (r & 7);
      sh[sb] = gh[blk];
      sl[sb] = gl[blk];
    }
  }

  // Z for my 8 pixel rows (C/D layout: row = quad*4 + reg)
  float Zr[8];
#pragma unroll
  for (int rt = 0; rt < 2; ++rt)
#pragma unroll
    for (int rr = 0; rr < 4; ++rr)
      Zr[rt * 4 + rr] = zsq[p0 + wh * 32 + rt * 16 + quad * 4 + rr];

  __syncthreads();

  float bs[8];
  int   bi[8];
#pragma unroll
  for (int j = 0; j < 8; ++j) { bs[j] = 3.0e38f; bi[j] = 0; }

  const f32x4 vzero = {0.0f, 0.0f, 0.0f, 0.0f};

  // ---- software-pipelined main loop: prefetch iter i+1 before compute i ----
  f16x8 B0[16], B1[16];
  LOADB(B0, 0);
#pragma unroll 1
  for (int tt = 0; tt < 16; ++tt) {
    int i0 = tt * 2, i1 = tt * 2 + 1;
    LOADB(B1, i1);
    COMPUTE(B0, i0);
    int inext = (i1 + 1 < 32) ? i1 + 1 : 31;   // clamp: one redundant reload at end
    LOADB(B0, inext);
    COMPUTE(B1, i1);
  }

  // ---- reduce: 16 lanes of each quad -> LDS -> across waves ----
  __syncthreads();                          // A-tile dead; reuse LDS
  unsigned long long* red = (unsigned long long*)smem;   // 4 waves x 32 rows
#pragma unroll
  for (int j = 0; j < 8; ++j) {
    float s = bs[j]; int i_ = bi[j];
#pragma unroll
    for (int m = 1; m <= 8; m <<= 1) {
      float s2 = __shfl_xor(s, m);
      int   i2 = __shfl_xor(i_, m);
      if (s2 < s || (s2 == s && i2 < i_)) { s = s2; i_ = i2; }
    }
    if (l15 == 0) {
      int row32 = ((j >> 2) << 4) + (quad << 2) + (j & 3);   // rt*16 + quad*4 + rr
      unsigned u = __float_as_uint(s);
      u = (u & 0x80000000u) ? ~u : (u | 0x80000000u);        // order-preserving map
      red[wave * 32 + row32] = ((unsigned long long)u << 32) | (unsigned)i_;
    }
  }
  __syncthreads();
  // waves (wh) and (wh+2) cover the same 32 pixel rows with disjoint codes
  if (wave == 0) {
    int wh2 = lane >> 5, r31 = lane & 31;
    unsigned long long a = red[wh2 * 32 + r31];
    unsigned long long b = red[(wh2 + 2) * 32 + r31];
    if (b < a) a = b;
    atomicMin(&best[p0 + lane], a);
  }
}

// ---------------- K3: gather quantized, write codes, accumulate loss ----------------
__global__ void k_gather(const float* __restrict__ z, const float* __restrict__ cb,
                         const unsigned long long* __restrict__ best,
                         float* __restrict__ out_codes, float* __restrict__ out_q,
                         float* __restrict__ lossac) {
  int b  = blockIdx.x >> 4;
  int cg = blockIdx.x & 15;
  int t  = threadIdx.x;
  int idx[4];
#pragma unroll
  for (int pi = 0; pi < 4; ++pi) {
    int p = t + pi * 256;
    unsigned long long pk = best[b * 1024 + p];
    idx[pi] = (int)(unsigned)(pk & 0xffffffffu);
    if (cg == 0) out_codes[b * 1024 + p] = (float)idx[pi];
  }
  float lsum = 0.0f;
#pragma unroll
  for (int ci = 0; ci < 16; ++ci) {
    int c = cg * 16 + ci;
#pragma unroll
    for (int pi = 0; pi < 4; ++pi) {
      int p = t + pi * 256;
      float q  = cb[(size_t)idx[pi] * CDIM + c];
      size_t o = ((size_t)(b * CDIM + c)) * 1024 + p;
      float zv = z[o];
      float d  = q - zv;
      out_q[o] = zv + d;                 // straight-through: same op order as reference
      lsum = fmaf(d, d, lsum);
    }
  }
#pragma unroll
  for (int m = 32; m >= 1; m >>= 1) lsum += __shfl_xor(lsum, m);
  __shared__ float wsum[4];
  if ((t & 63) == 0) wsum[t >> 6] = lsum;
  __syncthreads();
  if (t == 0) atomicAdd(lossac, wsum[0] + wsum[1] + wsum[2] + wsum[3]);
}

// ---------------- K4: finalize loss scalar ----------------
__global__ void k_final(const float* __restrict__ lossac, float* __restrict__ out_loss) {
  if (threadIdx.x == 0) out_loss[0] = lossac[0] * (1.25f / 4194304.0f);
}

extern "C" void kernel_launch(void* const* d_in, const int* in_sizes, int n_in,
                              void* d_out, int out_size, void* d_ws, size_t ws_size,
                              hipStream_t stream) {
  (void)in_sizes; (void)n_in; (void)out_size; (void)ws_size;
  const float* z  = (const float*)d_in[0];
  const float* cb = (const float*)d_in[1];
  float* outf = (float*)d_out;

  char* ws = (char*)d_ws;
  f16*   bfh  = (f16*)ws;                                   // 4 MB packed B-frag hi
  f16*   bfl  = (f16*)(ws + (4 << 20));                     // 4 MB packed B-frag lo
  float* esq  = (float*)(ws + (8 << 20));                   // 32 KB
  unsigned long long* best = (unsigned long long*)(ws + (8 << 20) + 32768);  // 128 KB
  float* lossac = (float*)(ws + (8 << 20) + 32768 + 131072);                 // 4 B (pad 256)
  float* zsq    = (float*)(ws + (8 << 20) + 32768 + 131072 + 256);           // 64 KB
  int*   cnt    = (int*)  (ws + (8 << 20) + 32768 + 131072 + 256 + 65536);   // 32 B

  // scratch inside d_out's quantized region (overwritten by k_gather afterwards)
  f16* zhi = (f16*)(outf + 16384);                          // 8 MB
  f16* zlo = zhi + (size_t)NPIX * CDIM;                     // 8 MB

  k_prep   <<<609,  256, 0,     stream>>>(z, cb, zhi, zlo, zsq, bfh, bfl, esq,
                                          best, lossac, cnt);
  k_score  <<<2048, 256, 65536, stream>>>(bfh, bfl, zhi, zlo, esq, zsq, cnt, best);
  k_gather <<<256,  256, 0,     stream>>>(z, cb, best, outf, outf + 16384, lossac);
  k_final  <<<1,    64,  0,     stream>>>(lossac, outf + 16384 + (size_t)NPIX * CDIM);
}